// Round 7
// baseline (760.091 us; speedup 1.0000x reference)
//
#include <hip/hip_runtime.h>
#include <hip/hip_cooperative_groups.h>
#include <math.h>

namespace cg = cooperative_groups;

constexpr int Bb = 64, Nn = 512, Vv = 64, Hh = 512, Rr = 4, Aa = 18, INp = 128, KTOP = 32;
constexpr int CIN = 384;   // IN + R*V
constexpr int WOUT = 195;  // 3V+3
constexpr int GRID = 256;
constexpr int NWAVE = GRID*4;      // 1024
constexpr int NTHRD = GRID*256;    // 65536
#define EPSf 1e-8f

__device__ __forceinline__ float sigmoidf(float x){ return 1.f/(1.f+expf(-x)); }
__device__ __forceinline__ float softplusf(float x){ return (x>20.f)? x : log1pf(expf(x)); }
__device__ __forceinline__ float wave_reduce(float v){
  #pragma unroll
  for(int o=32;o>0;o>>=1) v += __shfl_down(v, o, 64);
  return v;
}

// Workspace layout (floats)
constexpr int WS_RO     = 0;        // 17408
constexpr int WS_SC     = 17408;    // 131072 (raw: dot/mem_norm)
constexpr int WS_CW     = 148480;   // 131072
constexpr int WS_FW     = 279552;   // 131072
constexpr int WS_BWPART = 410624;   // 1048576
constexpr int WS_RVEC   = 1459200;  // 16384
constexpr int WS_GATES  = 1475584;  // 131072
constexpr int WS_WO     = 1606656;  // 12480
constexpr int WS_WSIM   = 1619136;  // 32768

__global__ __launch_bounds__(256, 2) void dnc_mega(
    const float* __restrict__ x, const float* __restrict__ h, const float* __restrict__ c,
    const float* __restrict__ mem, const float* __restrict__ rw, const float* __restrict__ wwt,
    const float* __restrict__ usage, const float* __restrict__ link, const float* __restrict__ prec,
    const float* __restrict__ Wih, const float* __restrict__ Whh,
    const float* __restrict__ bih, const float* __restrict__ bhh,
    const float* __restrict__ Wr, const float* __restrict__ br,
    const float* __restrict__ Ww, const float* __restrict__ bw_,
    const float* __restrict__ Wp, const float* __restrict__ bp,
    const float* __restrict__ Wv, const float* __restrict__ bv,
    float* __restrict__ out, float* __restrict__ ws) {
  cg::grid_group grid = cg::this_grid();
  __shared__ __align__(16) char smem[32768];

  const int tid = threadIdx.x;
  const int wv = tid >> 6, lane = tid & 63;
  const int blk = blockIdx.x;                 // 0..255
  const int gwave = blk*4 + wv;               // 0..1023
  const int gthread = blk*256 + tid;          // 0..65535

  float* o_logits = out + 0;
  float* o_value  = out + 1152;
  float* o_h      = out + 1216;
  float* o_c      = out + 33984;
  float* o_mem    = out + 66752;
  float* o_wr     = out + 2163904;
  float* o_ww     = out + 2294976;
  float* o_usage  = out + 2327744;
  float* o_link   = out + 2360512;
  float* o_prec   = out + 19137728;

  float* ws_ro     = ws + WS_RO;
  float* ws_sc     = ws + WS_SC;
  float* ws_cw     = ws + WS_CW;
  float* ws_fw     = ws + WS_FW;
  float* ws_bwpart = ws + WS_BWPART;
  float* ws_rvec   = ws + WS_RVEC;
  float* ws_gates  = ws + WS_GATES;
  float* ws_wo     = ws + WS_WO;
  float* ws_wsim   = ws + WS_WSIM;

  // ================= P0: read_proj (wave loop) + fwbw (unit loop) =================
  for (int u = gwave; u < Bb*272; u += NWAVE) {
    int b = u / 272, p = u % 272;
    const float* wrow = Wr + p*Hh;
    const float* hb = h + b*Hh;
    float acc = 0.f;
    #pragma unroll
    for (int t = 0; t < 8; ++t) { int k = lane + 64*t; acc += wrow[k]*hb[k]; }
    acc = wave_reduce(acc);
    if (lane == 0) ws_ro[b*272 + p] = acc + br[p];
  }
  for (int unit = blk; unit < 512; unit += GRID) {
    float (*bl)[4][512] = (float(*)[4][512])smem;   // 32 KB
    int b  = unit >> 3;
    int ch = unit & 7;
    const float* rwb = rw + b*Rr*Nn;
    float rwv[4][8];
    #pragma unroll
    for (int r = 0; r < 4; ++r)
      #pragma unroll
      for (int t = 0; t < 8; ++t) rwv[r][t] = rwb[r*512 + lane + 64*t];
    float bwacc[8][4] = {};
    const float* lb = link + (size_t)b*Nn*Nn;
    int n0 = ch*64 + wv*16;
    for (int i = 0; i < 16; ++i) {
      int n = n0 + i;
      float lk[8];
      #pragma unroll
      for (int t = 0; t < 8; ++t) lk[t] = lb[n*512 + lane + 64*t];
      float s0 = rwb[n], s1 = rwb[512+n], s2 = rwb[1024+n], s3 = rwb[1536+n];
      float f0=0,f1=0,f2=0,f3=0;
      #pragma unroll
      for (int t = 0; t < 8; ++t) {
        float lv = lk[t];
        f0 += lv*rwv[0][t]; f1 += lv*rwv[1][t]; f2 += lv*rwv[2][t]; f3 += lv*rwv[3][t];
        bwacc[t][0] += lv*s0; bwacc[t][1] += lv*s1; bwacc[t][2] += lv*s2; bwacc[t][3] += lv*s3;
      }
      f0 = wave_reduce(f0); f1 = wave_reduce(f1);
      f2 = wave_reduce(f2); f3 = wave_reduce(f3);
      if (lane == 0) {
        ws_fw[(b*Rr+0)*Nn+n] = f0; ws_fw[(b*Rr+1)*Nn+n] = f1;
        ws_fw[(b*Rr+2)*Nn+n] = f2; ws_fw[(b*Rr+3)*Nn+n] = f3;
      }
    }
    #pragma unroll
    for (int t = 0; t < 8; ++t)
      #pragma unroll
      for (int r = 0; r < 4; ++r) bl[wv][r][lane + 64*t] = bwacc[t][r];
    __syncthreads();
    #pragma unroll
    for (int q = 0; q < 8; ++q) {
      int idx = q*256 + tid;        // r*512 + j
      int r = idx >> 9, j = idx & 511;
      float v = bl[0][r][j] + bl[1][r][j] + bl[2][r][j] + bl[3][r][j];
      ws_bwpart[((size_t)(ch*Bb + b)*Rr + r)*Nn + j] = v;
    }
    __syncthreads();
  }
  grid.sync();

  // ================= P1: raw scores = dot/mem_norm (wave loop) =================
  for (int u = gwave; u < Bb*Nn; u += NWAVE) {
    int b = u >> 9, n = u & 511;
    float m = mem[u*Vv + lane];
    float mn = wave_reduce(m*m);
    #pragma unroll
    for (int r = 0; r < Rr; ++r) {
      float kv = ws_ro[b*272 + r*68 + lane];
      float s = wave_reduce(m*kv);
      if (lane == 0)
        ws_sc[(b*Rr + r)*Nn + n] = s / fmaxf(sqrtf(mn), EPSf);
    }
  }
  grid.sync();

  // ================= P2: topk + masked softmax -> cw (blocks 1:1, 256 units) =================
  {
    float* sv = (float*)smem;       // 512
    float* so = sv + 512;           // 512
    float* red = so + 512;          // 256
    float* sscale = red + 256;      // 1
    int b = blk >> 2, r = blk & 3;
    if (wv == 0) {
      float kv = ws_ro[b*272 + r*68 + lane];
      float k2 = wave_reduce(kv*kv);
      if (lane == 0) {
        float rbeta = softplusf(ws_ro[b*272 + r*68 + 64]);
        *sscale = rbeta / fmaxf(sqrtf(k2), EPSf);
      }
    }
    __syncthreads();
    float scale = *sscale;
    const float* srow = ws_sc + (b*Rr + r)*Nn;
    for (int i = tid; i < 512; i += 256) { float v = scale*srow[i]; sv[i]=v; so[i]=v; }
    __syncthreads();
    for (int k = 2; k <= 512; k <<= 1) {
      for (int j = k>>1; j > 0; j >>= 1) {
        for (int i = tid; i < 512; i += 256) {
          int ixj = i ^ j;
          if (ixj > i) {
            float a = sv[i], cc = sv[ixj];
            bool descSeg = ((i & k) == 0);
            bool sw = descSeg ? (a < cc) : (a > cc);
            if (sw) { sv[i]=cc; sv[ixj]=a; }
          }
        }
        __syncthreads();
      }
    }
    float kth = sv[KTOP-1];
    float mx = sv[0];
    float lsum = 0.f;
    for (int i = tid; i < 512; i += 256) {
      float v = so[i];
      lsum += (v >= kth) ? expf(v - mx) : 0.f;
    }
    red[tid] = lsum; __syncthreads();
    for (int s2 = 128; s2 > 0; s2 >>= 1) {
      if (tid < s2) red[tid] += red[tid+s2];
      __syncthreads();
    }
    float inv = 1.f / red[0];
    for (int i = tid; i < 512; i += 256) {
      float v = so[i];
      ws_cw[(b*Rr + r)*Nn + i] = (v >= kth) ? expf(v - mx)*inv : 0.f;
    }
    __syncthreads();
  }
  grid.sync();

  // ================= P3: w_r, psi, usage_new ; zero rvec =================
  if (gthread < Bb*Rr*Vv) ws_rvec[gthread] = 0.f;
  if (gthread < Bb*Nn) {
    int idx = gthread;
    int b = idx >> 9, n = idx & 511;
    float psi = 1.f;
    #pragma unroll
    for (int r = 0; r < Rr; ++r) {
      int brr = b*Rr + r;
      const float* rob = ws_ro + b*272 + r*68;
      float e0 = rob[65], e1 = rob[66], e2 = rob[67];
      float m = fmaxf(e0, fmaxf(e1, e2));
      float x0 = expf(e0-m), x1 = expf(e1-m), x2 = expf(e2-m);
      float inv = 1.f/(x0+x1+x2);
      float bwv = 0.f;
      #pragma unroll
      for (int chh = 0; chh < 8; ++chh)
        bwv += ws_bwpart[((size_t)(chh*Bb + b)*Rr + r)*Nn + n];
      float w = (x0*bwv + x1*ws_cw[brr*Nn+n] + x2*ws_fw[brr*Nn+n]) * inv;
      o_wr[brr*Nn+n] = w;
      psi *= (1.f - w);
    }
    float u = usage[idx], wt = wwt[idx];
    o_usage[idx] = (u + wt - u*wt) * psi;
  }
  grid.sync();

  // ================= P4: rvec (unit loop, atomic) =================
  for (int unit = blk; unit < 512; unit += GRID) {
    int b = unit >> 3;
    int ch = unit & 7;
    int r = wv, v = lane;
    const float* wrow = o_wr + (b*Rr + r)*Nn;
    const float* mb = mem + (size_t)b*Nn*Vv;
    float acc = 0.f;
    #pragma unroll 4
    for (int t = 0; t < 64; ++t) {
      int n = ch*64 + t;
      acc += wrow[n] * mb[n*Vv + v];
    }
    atomicAdd(&ws_rvec[(b*Rr+r)*Vv + v], acc);
  }
  grid.sync();

  // ================= P5: gates GEMM (4j x 4b tile per wave-unit) =================
  for (int u = gwave; u < 8192; u += NWAVE) {
    int jt = u >> 4;    // 0..511
    int bt = u & 15;    // 0..15
    float acc[4][4] = {};
    #pragma unroll
    for (int t = 0; t < 6; ++t) {
      int k = lane + 64*t;
      float uu[4], w[4];
      #pragma unroll
      for (int i = 0; i < 4; ++i) {
        int b = bt*4 + i;
        uu[i] = (k < INp) ? x[b*INp + k] : ws_rvec[b*(Rr*Vv) + k - INp];
        w[i] = Wih[(jt*4+i)*CIN + k];
      }
      #pragma unroll
      for (int jj = 0; jj < 4; ++jj)
        #pragma unroll
        for (int bb2 = 0; bb2 < 4; ++bb2) acc[jj][bb2] += w[jj]*uu[bb2];
    }
    #pragma unroll
    for (int t = 0; t < 8; ++t) {
      int k = lane + 64*t;
      float uu[4], w[4];
      #pragma unroll
      for (int i = 0; i < 4; ++i) {
        uu[i] = h[(bt*4+i)*Hh + k];
        w[i] = Whh[(jt*4+i)*Hh + k];
      }
      #pragma unroll
      for (int jj = 0; jj < 4; ++jj)
        #pragma unroll
        for (int bb2 = 0; bb2 < 4; ++bb2) acc[jj][bb2] += w[jj]*uu[bb2];
    }
    #pragma unroll
    for (int jj = 0; jj < 4; ++jj)
      #pragma unroll
      for (int bb2 = 0; bb2 < 4; ++bb2) {
        float v = wave_reduce(acc[jj][bb2]);
        if (lane == 0) {
          int j = jt*4 + jj, b = bt*4 + bb2;
          ws_gates[b*(4*Hh) + j] = v + bih[j] + bhh[j];
        }
      }
  }
  grid.sync();

  // ================= P6: LSTM elementwise =================
  if (gthread < Bb*Hh) {
    int idx = gthread;
    int b = idx >> 9, hh = idx & 511;
    const float* g = ws_gates + b*2048;
    float ig = sigmoidf(g[hh]), fg = sigmoidf(g[512+hh]);
    float gg = tanhf(g[1024+hh]), og = sigmoidf(g[1536+hh]);
    float cn = fg * c[idx] + ig * gg;
    float hn = og * tanhf(cn);
    o_c[idx] = cn; o_h[idx] = hn;
  }
  grid.sync();

  // ================= P7: wo + policy + value =================
  for (int u = gwave; u < Bb*214; u += NWAVE) {
    int b = u / 214, o = u % 214;
    const float* wrow;
    if (o < WOUT) wrow = Ww + o*Hh;
    else if (o < WOUT + Aa) wrow = Wp + (o-WOUT)*Hh;
    else wrow = Wv;
    const float* hb = o_h + b*Hh;
    float acc = 0.f;
    #pragma unroll
    for (int t = 0; t < 8; ++t) { int k = lane+64*t; acc += hb[k]*wrow[k]; }
    acc = wave_reduce(acc);
    if (lane == 0) {
      if (o < WOUT) ws_wo[b*WOUT+o] = acc + bw_[o];
      else if (o < WOUT + Aa) o_logits[b*Aa + (o-WOUT)] = acc + bp[o-WOUT];
      else o_value[b] = acc + bv[0];
    }
  }
  grid.sync();

  // ================= P8: wsim =================
  for (int u = gwave; u < Bb*Nn; u += NWAVE) {
    int b = u >> 9;
    const float* wob = ws_wo + b*WOUT;
    float kv = wob[lane];
    float m = mem[u*Vv + lane];
    float s  = wave_reduce(m*kv);
    float mn = wave_reduce(m*m);
    float k2 = wave_reduce(kv*kv);
    if (lane == 0) {
      float wbeta = softplusf(wob[192]);
      ws_wsim[u] = wbeta * s / (fmaxf(sqrtf(mn),EPSf) * fmaxf(sqrtf(k2),EPSf));
    }
  }
  grid.sync();

  // ================= P9: alloc (blocks 0..63) =================
  if (blk < 64) {
    float* uv = (float*)smem;            // 512
    int*   ui = (int*)(uv + 512);        // 512
    float* cp = (float*)(ui + 512);      // 512
    float* al = cp + 512;                // 512
    float* red = al + 512;               // 256
    int b = blk;
    float s0 = ws_wsim[b*Nn + tid], s1 = ws_wsim[b*Nn + tid + 256];
    red[tid] = fmaxf(s0, s1); __syncthreads();
    for (int s2=128; s2>0; s2>>=1){ if (tid<s2) red[tid]=fmaxf(red[tid],red[tid+s2]); __syncthreads(); }
    float mx = red[0]; __syncthreads();
    float e0 = expf(s0-mx), e1 = expf(s1-mx);
    red[tid] = e0+e1; __syncthreads();
    for (int s2=128; s2>0; s2>>=1){ if (tid<s2) red[tid]+=red[tid+s2]; __syncthreads(); }
    float cinv = 1.f/red[0];
    float c0 = e0*cinv, c1 = e1*cinv;
    __syncthreads();
    for (int i = tid; i < 512; i += 256) { uv[i] = usage[b*Nn+i]; ui[i] = i; }
    __syncthreads();
    for (int k = 2; k <= 512; k <<= 1) {
      for (int j = k>>1; j > 0; j >>= 1) {
        for (int i = tid; i < 512; i += 256) {
          int ixj = i ^ j;
          if (ixj > i) {
            float av = uv[i], bv2 = uv[ixj];
            int ai = ui[i], bi = ui[ixj];
            bool gt = (av > bv2) || (av == bv2 && ai > bi);
            bool asc = ((i & k) == 0);
            bool sw = asc ? gt : !gt;
            if (sw) { uv[i]=bv2; uv[ixj]=av; ui[i]=bi; ui[ixj]=ai; }
          }
        }
        __syncthreads();
      }
    }
    for (int i = tid; i < 512; i += 256) cp[i] = uv[i];
    __syncthreads();
    for (int d = 1; d < 512; d <<= 1) {
      float t0 = cp[tid]     * ((tid >= d)     ? cp[tid-d]     : 1.f);
      float t1 = cp[tid+256] * ((tid+256 >= d) ? cp[tid+256-d] : 1.f);
      __syncthreads();
      cp[tid] = t0; cp[tid+256] = t1;
      __syncthreads();
    }
    for (int i = tid; i < 512; i += 256) {
      float pp = (i == 0) ? 1.f : cp[i-1];
      al[ui[i]] = (1.f - uv[i]) * pp;
    }
    __syncthreads();
    float ga = sigmoidf(ws_wo[b*WOUT+193]);
    float gw = sigmoidf(ws_wo[b*WOUT+194]);
    int n0 = tid, n1 = tid+256;
    float wv0 = gw * (ga*al[n0] + (1.f-ga)*c0);
    float wv1 = gw * (ga*al[n1] + (1.f-ga)*c1);
    o_ww[b*Nn+n0] = wv0; o_ww[b*Nn+n1] = wv1;
    red[tid] = wv0 + wv1; __syncthreads();
    for (int s2=128; s2>0; s2>>=1){ if (tid<s2) red[tid]+=red[tid+s2]; __syncthreads(); }
    float wsum = red[0];
    o_prec[b*Nn+n0] = (1.f - wsum)*prec[b*Nn+n0] + wv0;
    o_prec[b*Nn+n1] = (1.f - wsum)*prec[b*Nn+n1] + wv1;
  }
  grid.sync();

  // ================= P10: link_new + mem_new (float4, thread loop) =================
  // NOTE: link_new uses the OLD precedence weights (input `prec`), not o_prec.
  for (int u = gthread; u < 4718592; u += NTHRD) {
    if (u < 4194304) {
      int base = u*4;
      int b = base >> 18;
      int rem = base & 262143;
      int i = rem >> 9;
      int j0 = rem & 511;
      float wi = o_ww[b*Nn + i];
      float fi = 1.f - wi;
      float4 lv = *(const float4*)(link + base);
      float4 wj = *(const float4*)(o_ww + b*Nn + j0);
      float4 pj = *(const float4*)(prec + b*Nn + j0);
      float4 o;
      o.x = fi*(1.f-wj.x)*lv.x + wi*pj.x;
      o.y = fi*(1.f-wj.y)*lv.y + wi*pj.y;
      o.z = fi*(1.f-wj.z)*lv.z + wi*pj.z;
      o.w = fi*(1.f-wj.w)*lv.w + wi*pj.w;
      if (i >= j0 && i < j0+4) {
        if (i == j0) o.x = 0.f;
        else if (i == j0+1) o.y = 0.f;
        else if (i == j0+2) o.z = 0.f;
        else o.w = 0.f;
      }
      *(float4*)(o_link + base) = o;
    } else {
      int base = (u - 4194304)*4;
      int b = base >> 15;
      int rem = base & 32767;
      int v0 = rem & 63;
      int n = rem >> 6;
      float w = o_ww[b*Nn + n];
      const float* wob = ws_wo + b*WOUT;
      float4 m = *(const float4*)(mem + base);
      float4 o;
      float e, a;
      e = sigmoidf(wob[64+v0+0]); a = tanhf(wob[128+v0+0]); o.x = m.x*(1.f-w*e)+w*a;
      e = sigmoidf(wob[64+v0+1]); a = tanhf(wob[128+v0+1]); o.y = m.y*(1.f-w*e)+w*a;
      e = sigmoidf(wob[64+v0+2]); a = tanhf(wob[128+v0+2]); o.z = m.z*(1.f-w*e)+w*a;
      e = sigmoidf(wob[64+v0+3]); a = tanhf(wob[128+v0+3]); o.w = m.w*(1.f-w*e)+w*a;
      *(float4*)(o_mem + base) = o;
    }
  }
}

extern "C" void kernel_launch(void* const* d_in, const int* in_sizes, int n_in,
                              void* d_out, int out_size, void* d_ws, size_t ws_size,
                              hipStream_t stream) {
  const float* x    = (const float*)d_in[0];
  const float* h    = (const float*)d_in[1];
  const float* c    = (const float*)d_in[2];
  const float* mem  = (const float*)d_in[3];
  const float* rw   = (const float*)d_in[4];
  const float* wwt  = (const float*)d_in[5];
  const float* usage= (const float*)d_in[6];
  const float* link = (const float*)d_in[7];
  const float* prec = (const float*)d_in[8];
  const float* Wih  = (const float*)d_in[9];
  const float* Whh  = (const float*)d_in[10];
  const float* bih  = (const float*)d_in[11];
  const float* bhh  = (const float*)d_in[12];
  const float* Wr   = (const float*)d_in[13];
  const float* br   = (const float*)d_in[14];
  const float* Ww   = (const float*)d_in[15];
  const float* bw_  = (const float*)d_in[16];
  const float* Wp   = (const float*)d_in[17];
  const float* bp   = (const float*)d_in[18];
  const float* Wv   = (const float*)d_in[19];
  const float* bv   = (const float*)d_in[20];
  float* out = (float*)d_out;
  float* ws  = (float*)d_ws;

  void* kargs[] = {
    (void*)&x, (void*)&h, (void*)&c, (void*)&mem, (void*)&rw, (void*)&wwt,
    (void*)&usage, (void*)&link, (void*)&prec, (void*)&Wih, (void*)&Whh,
    (void*)&bih, (void*)&bhh, (void*)&Wr, (void*)&br, (void*)&Ww, (void*)&bw_,
    (void*)&Wp, (void*)&bp, (void*)&Wv, (void*)&bv, (void*)&out, (void*)&ws
  };
  hipLaunchCooperativeKernel((void*)dnc_mega, dim3(GRID), dim3(256), kargs, 0, stream);
}